// Round 13
// baseline (344.127 us; speedup 1.0000x reference)
//
#include <hip/hip_runtime.h>
#include <hip/hip_bf16.h>
#include <hip/hip_fp16.h>

// ---------------------------------------------------------------------------
// EnhancedRGCN (3-layer GAT), N=100000 nodes, E=3200000 edges, D=32.
// CSR-by-dst via FIXED-CAPACITY bucket binning (bucket = dst>>7, 128 nodes,
// CAPB=6144 slots): no histogram pre-pass, no bucket scan; cursors are
// RELATIVE (memset 0) so no init kernel.
// k_bin: 1024 threads x 8 edges, 32B-rounded cursor reservations w/ sentinel
// pad. k_bucket_sort: 512 threads, LDS-staged, 4-way replicated bin counters
// (cuts same-address LDS-atomic serialization), coalesced int4 writeback.
// k_edge: two nodes per wave (half-wave per node, R12); pass B gathers
// 32 edges/node/iteration = 8 ds_read_b128 + 16 half2 gathers in flight
// (R12 PMC: VALUBusy 50% -> latency x MLP bound; widen the window).
// No segment-max (shift-invariant softmax, bounded logits); no float atomics.
// ---------------------------------------------------------------------------

#define NPB  128    // nodes per bucket (dst>>7)
#define CAPB 6144   // slots per bucket (mean ~5475 incl. pad, >9 sigma room)
#define PAD_SENTINEL 0xFFFFFFFFu

// ---------------- pass 1: bin edges into fixed bucket regions --------------
// Relative cursors (pre-memset to 0); absolute base = b*CAPB at use.
__global__ void __launch_bounds__(1024)
k_bin(const int* __restrict__ src, const int* __restrict__ dst,
      int* __restrict__ bucket_cursor, unsigned int* __restrict__ pairs,
      int e, int nb) {
    const int EPT = 8;
    __shared__ int h[1024];
    __shared__ int cbase[1024];
    __shared__ int room[1024];
    int t = threadIdx.x;
    for (int i = t; i < nb; i += 1024) h[i] = 0;
    __syncthreads();
    int e4 = e >> 2;
    int base4 = blockIdx.x * 2048;   // 1024 threads x 2 int4 each
    int boff[EPT];                   // (bucket<<16) | offset, or -1
    unsigned int pk[EPT];
#pragma unroll
    for (int k = 0; k < 2; k++) {
        int i4 = base4 + k * 1024 + t;
        if (i4 < e4) {
            int4 dv = ((const int4*)dst)[i4];
            int4 sv = ((const int4*)src)[i4];
            const int* dd = (const int*)&dv;
            const int* ss = (const int*)&sv;
#pragma unroll
            for (int j = 0; j < 4; j++) {
                int q = 4 * k + j;
                int d = dd[j];
                int b = d >> 7;
                pk[q] = ((unsigned int)ss[j] << 7) | (unsigned int)(d & 127);
                int off = atomicAdd(&h[b], 1);
                boff[q] = (b << 16) | off;
            }
        } else {
#pragma unroll
            for (int j = 0; j < 4; j++) boff[4 * k + j] = -1;
        }
    }
    __syncthreads();
    for (int i = t; i < nb; i += 1024) {
        int c = h[i];
        if (c) {
            int r = (c + 7) & ~7;                    // round to 8 slots (32B)
            int cbr = atomicAdd(&bucket_cursor[i], r);
            int rm = CAPB - cbr;                     // overflow guard
            int ab = i * CAPB + cbr;
            cbase[i] = ab;
            room[i] = rm;
            for (int j = c; j < r && j < rm; j++)    // sentinel-fill the pad
                pairs[ab + j] = PAD_SENTINEL;
        }
    }
    __syncthreads();
#pragma unroll
    for (int q = 0; q < EPT; q++) {
        if (boff[q] >= 0) {
            int b = boff[q] >> 16;
            int off = boff[q] & 0xFFFF;
            if (off < room[b]) pairs[cbase[b] + off] = pk[q];
        }
    }
    if (blockIdx.x == 0 && t < (e & 3)) {
        int i = (e & ~3) + t;
        int d = dst[i];
        int b = d >> 7;
        int posr = atomicAdd(&bucket_cursor[b], 1);
        if (posr < CAPB)
            pairs[b * CAPB + posr] = ((unsigned int)src[i] << 7) | (unsigned int)(d & 127);
    }
}

// ---------------- pass 2: per-bucket LDS sort -> rowinfo + src_sorted ------
// 4-way replicated bin counters: thread t uses replica t&3 in BOTH the count
// and rank passes (same elements -> consistent ranks); per-replica exclusive
// offsets derived in the scan. LDS-staged pairs; coalesced int4 writeback.
__global__ void __launch_bounds__(512)
k_bucket_sort(const unsigned int* __restrict__ pairs,
              const int* __restrict__ bucket_cursor,
              int2* __restrict__ rowinfo, int* __restrict__ src_sorted,
              int n) {
    __shared__ int cnt4[NPB][4];
    __shared__ int cur4[NPB][4];
    __shared__ int total;
    __shared__ unsigned int lp[CAPB];
    __shared__ int op[CAPB];
    int b = blockIdx.x;
    int t = threadIdx.x;
    int rep = t & 3;
    int bbase = b * CAPB;
    int m = bucket_cursor[b];
    if (m > CAPB) m = CAPB;
    if (t < NPB) { cnt4[t][0] = 0; cnt4[t][1] = 0; cnt4[t][2] = 0; cnt4[t][3] = 0; }
    __syncthreads();
    // counting + LDS staging, 8-deep batches
    for (int cb = 0; cb < m; cb += 4096) {
        unsigned int pv[8];
#pragma unroll
        for (int u = 0; u < 8; u++) {
            int i = cb + u * 512 + t;
            pv[u] = (i < m) ? pairs[bbase + i] : PAD_SENTINEL;
        }
#pragma unroll
        for (int u = 0; u < 8; u++) {
            int i = cb + u * 512 + t;
            if (i < m) lp[i] = pv[u];
            if (pv[u] != PAD_SENTINEL) atomicAdd(&cnt4[pv[u] & 127][rep], 1);
        }
    }
    __syncthreads();
    if (t < 64) {                       // wave 0: shfl scan over 128 bins
        int q0[4], q1[4];
#pragma unroll
        for (int j = 0; j < 4; j++) { q0[j] = cnt4[2 * t][j]; q1[j] = cnt4[2 * t + 1][j]; }
        int c0 = q0[0] + q0[1] + q0[2] + q0[3];
        int c1 = q1[0] + q1[1] + q1[2] + q1[3];
        int sum = c0 + c1;
        int run = sum;
#pragma unroll
        for (int off = 1; off < 64; off <<= 1) {
            int v = __shfl_up(run, off, 64);
            if (t >= off) run += v;
        }
        int ex = run - sum;             // exclusive across bins
        // per-replica exclusive offsets within each bin
        int o = ex;
#pragma unroll
        for (int j = 0; j < 4; j++) { cur4[2 * t][j] = o; o += q0[j]; }
#pragma unroll
        for (int j = 0; j < 4; j++) { cur4[2 * t + 1][j] = o; o += q1[j]; }
        int node = b * NPB + 2 * t;
        if (node < n) rowinfo[node] = make_int2(bbase + ex, c0);
        if (node + 1 < n) rowinfo[node + 1] = make_int2(bbase + ex + c0, c1);
        if (t == 63) total = run;       // dense entry count
    }
    __syncthreads();
    // rank + scatter LDS->LDS, 8-deep batches
    for (int cb = 0; cb < m; cb += 4096) {
        unsigned int pv[8];
        int of[8];
#pragma unroll
        for (int u = 0; u < 8; u++) {
            int i = cb + u * 512 + t;
            pv[u] = (i < m) ? lp[i] : PAD_SENTINEL;
        }
#pragma unroll
        for (int u = 0; u < 8; u++)
            if (pv[u] != PAD_SENTINEL) of[u] = atomicAdd(&cur4[pv[u] & 127][rep], 1);
#pragma unroll
        for (int u = 0; u < 8; u++)
            if (pv[u] != PAD_SENTINEL) op[of[u]] = (int)(pv[u] >> 7);
    }
    __syncthreads();
    int nt4 = (total + 3) >> 2;
    int4* dst4 = (int4*)(src_sorted + bbase);
    const int4* src4 = (const int4*)op;
    for (int i = t; i < nt4; i += 512) dst4[i] = src4[i];
}

// ---------------- per-layer dense transform ----------------
template <int H>
__global__ void k_transform(const float* __restrict__ in, const float* __restrict__ W,
                            const float* __restrict__ att_s, const float* __restrict__ att_d,
                            __half* __restrict__ h16, float* __restrict__ a_s,
                            float* __restrict__ a_d, int n) {
    constexpr int C = 32 / H;
    __shared__ float Wl[32][33];
    __shared__ float xs[8][32];
    int t = threadIdx.x;
    for (int i = t; i < 1024; i += 256) Wl[i >> 5][i & 31] = W[i];
    int nl = t >> 5, o = t & 31;
    int node = blockIdx.x * 8 + nl;
    xs[nl][o] = (node < n) ? in[node * 32 + o] : 0.f;
    __syncthreads();
    float acc = 0.f;
#pragma unroll
    for (int k = 0; k < 32; k++) acc = fmaf(xs[nl][k], Wl[o][k], acc);
    if (node < n) {
        h16[node * 32 + o] = __float2half_rn(acc);
        float vs = acc * att_s[o];
        float vd = acc * att_d[o];
#pragma unroll
        for (int m = C / 2; m >= 1; m >>= 1) {
            vs += __shfl_xor(vs, m, 64);
            vd += __shfl_xor(vd, m, 64);
        }
        if ((o % C) == 0) {
            int hh = o / C;
            a_s[node * H + hh] = vs;
            a_d[node * H + hh] = vd;
        }
    }
}

// ---------------- per-layer fused edge softmax + aggregation ----------------
// TWO NODES PER WAVE (half-wave per node). 8 nodes per 256-block.
// Pass A: half-wave lane-per-edge (stride 32), stash (s,ex) per head in LDS
//         zero-padded to mult of 32; denominator partials.
// Pass B: 2 slots x 16 channel-lanes per node; 32 edges/node/iteration via
//         8 ds_read_b128 + 16 half2 gathers in flight + 32 fma_mix.
// Denominator: 5-level half-wave butterfly after pass B; acc: 1 level.
// EPI: 0 = bias only (layer3), 1 = layer1 epilogue, 2 = elu+clip (layer2).
template <int H, int EPI>
__global__ void k_edge(const int2* __restrict__ rowinfo, const int* __restrict__ src_sorted,
                       const __half* __restrict__ h16,
                       const float* __restrict__ a_s, const float* __restrict__ a_d,
                       const float* __restrict__ bias, const float* __restrict__ ea,
                       float* __restrict__ out, int n, float slope) {
    constexpr int CAP = 128;                  // entries per node per head
    constexpr int RSTR = 2 * CAP + 16;        // region stride in ints (+64B pad)
    __shared__ int lds_raw[8][H][RSTR];
    int nw = threadIdx.x >> 5;                // node slot 0..7
    int hl = threadIdx.x & 31;                // half-wave lane
    int node = blockIdx.x * 8 + nw;
    if (node >= n) return;
    int2 bi = rowinfo[node];
    int beg = bi.x, deg = bi.y;
    int padB = (deg + 31) & ~31;

    float ad[H];
#pragma unroll
    for (int hh = 0; hh < H; hh++) ad[hh] = a_d[node * H + hh];

    // ---- pass A: stash (s, ex) per head + denominator partials ----
    float ds[H];
#pragma unroll
    for (int hh = 0; hh < H; hh++) ds[hh] = 0.f;
    bool fast = (padB <= CAP);
    if (fast) {
        for (int idx = hl; idx < padB; idx += 32) {
            if (idx < deg) {
                int s = src_sorted[beg + idx];
                if (H == 2) {
                    float2 as2 = *(const float2*)((const char*)a_s + (unsigned)(s << 3));
                    float l0 = as2.x + ad[0]; l0 = fmaxf(l0, l0 * slope);
                    float l1 = as2.y + ad[1]; l1 = fmaxf(l1, l1 * slope);
                    float e0 = __expf(l0), e1 = __expf(l1);
                    ds[0] += e0; ds[1] += e1;
                    ((int2*)lds_raw[nw][0])[idx] = make_int2(s, __float_as_int(e0));
                    ((int2*)lds_raw[nw][H - 1])[idx] = make_int2(s, __float_as_int(e1));
                } else {
                    float l0 = a_s[s] + ad[0]; l0 = fmaxf(l0, l0 * slope);
                    float e0 = __expf(l0);
                    ds[0] += e0;
                    ((int2*)lds_raw[nw][0])[idx] = make_int2(s, __float_as_int(e0));
                }
            } else {
#pragma unroll
                for (int hh = 0; hh < H; hh++)
                    ((int2*)lds_raw[nw][hh])[idx] = make_int2(0, 0);
            }
        }
    } else {
        for (int idx = hl; idx < deg; idx += 32) {
            int s = src_sorted[beg + idx];
            if (H == 2) {
                float2 as2 = *(const float2*)((const char*)a_s + (unsigned)(s << 3));
                float l0 = as2.x + ad[0]; l0 = fmaxf(l0, l0 * slope);
                float l1 = as2.y + ad[1]; l1 = fmaxf(l1, l1 * slope);
                ds[0] += __expf(l0); ds[1] += __expf(l1);
            } else {
                float l0 = a_s[s] + ad[0]; l0 = fmaxf(l0, l0 * slope);
                ds[0] += __expf(l0);
            }
        }
    }

    // ---- pass B: 2 slots x 16 lanes per node; 32 edges/node/iteration ----
    int e2 = hl >> 4;          // slot 0/1
    int l16 = hl & 15;         // channel pair 0..15
    int hd = (H == 2) ? (l16 >> 3) : 0;
    int co = l16 << 2;
    float adh = ad[hd];
    float acc0 = 0.f, acc1 = 0.f;
    const char* hbase = (const char*)h16;
    const int* lb = &lds_raw[nw][hd][e2 * 4];   // entry offset 2*e2

    if (fast) {
        // slot e2 covers entries base + {4k + 2*e2, 4k + 2*e2 + 1}, k=0..7
        for (int base = 0; base < padB; base += 32) {
            int4 q[8];
#pragma unroll
            for (int k = 0; k < 8; k++) q[k] = *(const int4*)(lb + base * 2 + 8 * k);
            __half2 hv[16];
#pragma unroll
            for (int k = 0; k < 8; k++) {
                hv[2 * k]     = *(const __half2*)(hbase + (unsigned)((q[k].x << 6) + co));
                hv[2 * k + 1] = *(const __half2*)(hbase + (unsigned)((q[k].z << 6) + co));
            }
#pragma unroll
            for (int k = 0; k < 8; k++) {
                float x0 = __int_as_float(q[k].y), x1 = __int_as_float(q[k].w);
                acc0 = fmaf(x0, __half2float(__low2half(hv[2 * k])), acc0);
                acc1 = fmaf(x0, __half2float(__high2half(hv[2 * k])), acc1);
                acc0 = fmaf(x1, __half2float(__low2half(hv[2 * k + 1])), acc0);
                acc1 = fmaf(x1, __half2float(__high2half(hv[2 * k + 1])), acc1);
            }
        }
    } else {
        for (int base = 0; base < deg; base += 16) {
#pragma unroll
            for (int u = 0; u < 8; u++) {
                int idx = base + u * 2 + e2;
                int s = 0;
                float ex = 0.f;
                if (idx < deg) {
                    s = src_sorted[beg + idx];
                    float l = a_s[s * H + hd] + adh;
                    l = fmaxf(l, l * slope);
                    ex = __expf(l);
                }
                __half2 hv = *(const __half2*)(hbase + (unsigned)((s << 6) + co));
                acc0 = fmaf(ex, __half2float(__low2half(hv)), acc0);
                acc1 = fmaf(ex, __half2float(__high2half(hv)), acc1);
            }
        }
    }

    // ---- denominator reduction (5-level half-wave butterfly, deferred) ----
#pragma unroll
    for (int hh = 0; hh < H; hh++) {
        float v = ds[hh];
#pragma unroll
        for (int m = 16; m >= 1; m >>= 1) v += __shfl_xor(v, m, 64);
        ds[hh] = 1.f / (v + 1e-16f);
    }

    // ---- reduce accs across the 2 slots (1 level) ----
    acc0 += __shfl_xor(acc0, 16, 64);
    acc1 += __shfl_xor(acc1, 16, 64);

    if (l16 == hl) {           // hl < 16: slot-0 lanes hold the result
        float invd = ds[hd];
        float2 bv = *(const float2*)(bias + l16 * 2);
        float v0 = fmaf(acc0, invd, bv.x);
        float v1 = fmaf(acc1, invd, bv.y);
        if (EPI == 1) {
            float s0 = tanhf(ea[0]);
            if (s0 < 0.1f) s0 = 1.0f;
            s0 *= 1.05f;
            v0 *= s0; v1 *= s0;
            v0 = (v0 > 0.f) ? v0 : expm1f(v0);
            v1 = (v1 > 0.f) ? v1 : expm1f(v1);
            v0 = fminf(3.f, fmaxf(-3.f, v0));
            v1 = fminf(3.f, fmaxf(-3.f, v1));
        } else if (EPI == 2) {
            v0 = (v0 > 0.f) ? v0 : expm1f(v0);
            v1 = (v1 > 0.f) ? v1 : expm1f(v1);
            v0 = fminf(3.f, fmaxf(-3.f, v0));
            v1 = fminf(3.f, fmaxf(-3.f, v1));
        }
        *(float2*)(out + (size_t)node * 32 + l16 * 2) = make_float2(v0, v1);
    }
}

// ---------------------------------------------------------------------------
extern "C" void kernel_launch(void* const* d_in, const int* in_sizes, int n_in,
                              void* d_out, int out_size, void* d_ws, size_t ws_size,
                              hipStream_t stream) {
    const float* x   = (const float*)d_in[0];
    const int*   ei  = (const int*)d_in[1];
    const float* W1  = (const float*)d_in[2];
    const float* as1 = (const float*)d_in[3];
    const float* ad1 = (const float*)d_in[4];
    const float* b1  = (const float*)d_in[5];
    const float* ea1 = (const float*)d_in[6];
    const float* W2  = (const float*)d_in[7];
    const float* as2 = (const float*)d_in[8];
    const float* ad2 = (const float*)d_in[9];
    const float* b2  = (const float*)d_in[10];
    const float* W3  = (const float*)d_in[11];
    const float* as3 = (const float*)d_in[12];
    const float* ad3 = (const float*)d_in[13];
    const float* b3  = (const float*)d_in[14];
    float* out = (float*)d_out;

    const int n = in_sizes[0] / 32;   // 100000
    const int e = in_sizes[1] / 2;    // 3200000
    const int* src = ei;
    const int* dst = ei + e;
    const int nb = (n + NPB - 1) / NPB;   // 782 buckets

    char* w = (char*)d_ws;
    auto alloc = [&](size_t bytes) -> void* {
        void* p = (void*)w;
        w += (bytes + 255) & ~(size_t)255;
        return p;
    };
    __half* h16     = (__half*)alloc((size_t)n * 32 * 2);
    float* a_s      = (float*)alloc((size_t)n * 2 * 4);
    float* a_d      = (float*)alloc((size_t)n * 2 * 4);
    float* bufA     = (float*)alloc((size_t)n * 32 * 4);
    float* bufB     = (float*)alloc((size_t)n * 32 * 4);
    int2* rowinfo   = (int2*)alloc((size_t)n * 8);
    int* bucket_cur = (int*)alloc((size_t)(nb + 1) * 4);
    int* src_sorted = (int*)alloc((size_t)nb * CAPB * 4);
    unsigned int* pairs = (unsigned int*)bufA;   // aliased; consumed pre-layer1

    // ---- build CSR by dst (fixed-capacity bucket binning) ----
    hipMemsetAsync(bucket_cur, 0, (size_t)nb * 4, stream);
    int e4 = e >> 2;
    k_bin<<<(e4 + 2047) / 2048, 1024, 0, stream>>>(src, dst, bucket_cur, pairs, e, nb);
    k_bucket_sort<<<nb, 512, 0, stream>>>(pairs, bucket_cur, rowinfo, src_sorted, n);

    const int tgrid = (n + 7) / 8;
    const int egrid = (n + 7) / 8;

    // ---- layer 1 ----
    k_transform<2><<<tgrid, 256, 0, stream>>>(x, W1, as1, ad1, h16, a_s, a_d, n);
    k_edge<2, 1><<<egrid, 256, 0, stream>>>(rowinfo, src_sorted, h16, a_s, a_d, b1, ea1, bufA, n, 0.01f);

    // ---- layer 2 ----
    k_transform<2><<<tgrid, 256, 0, stream>>>(bufA, W2, as2, ad2, h16, a_s, a_d, n);
    k_edge<2, 2><<<egrid, 256, 0, stream>>>(rowinfo, src_sorted, h16, a_s, a_d, b2, nullptr, bufB, n, 0.2f);

    // ---- layer 3 ----
    k_transform<1><<<tgrid, 256, 0, stream>>>(bufB, W3, as3, ad3, h16, a_s, a_d, n);
    k_edge<1, 0><<<egrid, 256, 0, stream>>>(rowinfo, src_sorted, h16, a_s, a_d, b3, nullptr, out, n, 0.2f);
}